// Round 5
// baseline (237.583 us; speedup 1.0000x reference)
//
#include <hip/hip_runtime.h>

// ---------------------------------------------------------------------------
// MultiHeadAttention: B=2, S=2048, H=16, Dh=64, D=1024, causal mask, fp32 I/O.
// R15: attention K/V staging DOUBLE-BUFFERED (T3/T14 minimum pipeline).
//      R14 counters: attn 49us with MfmaUtil 14 / VALU 36 / occ 12 / HBM 5%
//      => latency-serialized: 2 barriers/pair + vmcnt(0) drain put the full
//      HBM/L2 latency on the critical path each pair; jb=0 CUs run a 16-pair
//      block ALONE (1 wave/SIMD, no overlap).  Now: issue K-DMA(t+1) + V(t+1)
//      global loads before compute(t), write V regs->LDS after, ONE barrier
//      per pair.  LDS 2x32KB, compute/swizzles/mask byte-identical to R14.
//      GEMMs unchanged (R14 conflict-free swizzled staging, verified).
// ---------------------------------------------------------------------------

#define B_   2
#define S_   2048
#define H_   16
#define DH_  64
#define D_   1024
#define M_   (B_ * S_)          // 4096 rows

typedef __attribute__((ext_vector_type(8))) short short8;
typedef __attribute__((ext_vector_type(4))) short short4_t;
typedef float v4f __attribute__((ext_vector_type(4)));

__device__ __forceinline__ short f2bf(float f) {
    union { float f; unsigned u; } v; v.f = f;
    unsigned r = v.u + 0x7fffu + ((v.u >> 16) & 1u);  // round-to-nearest-even
    return (short)(r >> 16);
}

#if __has_builtin(__builtin_amdgcn_exp2f)
#define EXP2(x) __builtin_amdgcn_exp2f(x)
#else
#define EXP2(x) exp2f(x)
#endif

// pack two f32 -> dword of two truncated bf16 (low short = a, high = b)
__device__ __forceinline__ unsigned pack2(float a, float b) {
    return (__float_as_uint(a) >> 16) | (__float_as_uint(b) & 0xFFFF0000u);
}

// async 16B/lane global -> LDS DMA (lane l deposits at lds + l*16)
__device__ __forceinline__ void gl2lds16(const short* g, short* l) {
    __builtin_amdgcn_global_load_lds(
        (const __attribute__((address_space(1))) unsigned int*)g,
        (__attribute__((address_space(3))) unsigned int*)l,
        16, 0, 0);
}

// ---------------------------------------------------------------------------
// Kernel 1: cast X and Wq,Wk,Wv,Wo fp32 -> bf16.  8 elems/thread, 16B stores.
// ---------------------------------------------------------------------------
__global__ __launch_bounds__(256) void cast_kernel(
    const float* __restrict__ X,
    const float* __restrict__ Wq, const float* __restrict__ Wk,
    const float* __restrict__ Wv, const float* __restrict__ Wo,
    short* __restrict__ Xb, short* __restrict__ Wb)
{
    const int NX8 = (M_ * D_) / 8;      // 524,288
    const int NW8 = (D_ * D_) / 8;      // 131,072
    int idx = blockIdx.x * 256 + threadIdx.x;   // 1,048,576 threads

    const float* src; short* dst; int off;
    if (idx < NX8) { src = X; dst = Xb; off = idx; }
    else {
        int r = idx - NX8;
        int sel = r >> 17;
        int o = r & (NW8 - 1);
        src = (sel == 0) ? Wq : (sel == 1) ? Wk : (sel == 2) ? Wv : Wo;
        dst = Wb + sel * (D_ * D_);
        off = o;
    }
    float4 f0 = ((const float4*)src)[off * 2];
    float4 f1 = ((const float4*)src)[off * 2 + 1];
    short8 s;
    s[0] = f2bf(f0.x); s[1] = f2bf(f0.y); s[2] = f2bf(f0.z); s[3] = f2bf(f0.w);
    s[4] = f2bf(f1.x); s[5] = f2bf(f1.y); s[6] = f2bf(f1.z); s[7] = f2bf(f1.w);
    *(short8*)(dst + (size_t)off * 8) = s;
}

// ---------------------------------------------------------------------------
// Kernel 2: C = A(bf16,[M,K]) @ W(bf16,[N,K])^T + bias.  BM=128, BK=64.
// m97 staging into XOR-16B-chunk-SWIZZLED LDS tiles: gl2lds dest linear,
// global source chunk = (lane&7)^rsub; fragment read chunk = (kk*4+lg)^(lm&7)
// MODE 0 (BN=128): fused QKV, N=3072.  Q,K natural [bh][s][64]; V -> Vt
//                  [bh][64][s] via transposed LDS epilogue, 16B/lane stores.
//                  Q is PRE-SCALED by 0.125*log2(e) (attn exp2-domain fold).
// MODE 2 (BN=64):  fp32 out [M,1024] (final projection), 512 blocks (2/CU).
// XCD-aware flat-grid swizzle: xcd=bid&7 owns 4 m-rows.
// ---------------------------------------------------------------------------
template<int BN, int MODE>
__global__ __launch_bounds__(256) void gemm_kernel(
    const short* __restrict__ A, const short* __restrict__ W,
    const float* __restrict__ bq, const float* __restrict__ bk,
    const float* __restrict__ bv, void* __restrict__ out,
    int M, int N, int K)
{
    constexpr int SM = (MODE == 0) ? 18432 : (8192 + BN * 64);
    __shared__ __align__(16) short smem[SM];
    short* As = smem;                                  // [128][64] swizzled
    short* Bs = smem + 8192;                           // [BN][64]  swizzled

    const int t    = threadIdx.x;
    const int lane = t & 63;
    const int wave = t >> 6;

    const int bid = blockIdx.x;
    const int by  = ((bid & 7) << 2) + ((bid >> 3) & 3);
    const int bx  = bid >> 5;
    const int m0 = by * 128;
    const int n0 = bx * BN;

    const int wm = (wave >> 1) * 64;
    const int wn = (wave & 1) * (BN / 2);
    constexpr int NJ  = BN / 32;       // acc cols per wave (4 or 2)
    constexpr int BIT = BN / 32;       // B staging insts per wave

    v4f acc[4][NJ] = {};

    // staging: inst i2 covers 8 rows; lane l -> row +(l>>3),
    // SOURCE chunk ((l&7)^(l>>3))*8 shorts  (inverse of the read swizzle)
    const int rsub = lane >> 3;
    const int csw  = ((lane & 7) ^ rsub) * 8;
    const short* Ag = A + (size_t)(m0 + wave * 32 + rsub) * K + csw;
    const short* Wg = W + (size_t)(n0 + wave * (BN / 4) + rsub) * K + csw;
    short* Asw = As + (wave * 32) * 64;
    short* Bsw = Bs + (wave * (BN / 4)) * 64;

    const int lm = lane & 15;
    const int lg = lane >> 4;
    const int lm7 = lm & 7;

    for (int k0 = 0; k0 < K; k0 += 64) {
        #pragma unroll
        for (int i2 = 0; i2 < 4; ++i2)
            gl2lds16(Ag + (size_t)(i2 * 8) * K + k0, Asw + i2 * 512);
        #pragma unroll
        for (int i2 = 0; i2 < BIT; ++i2)
            gl2lds16(Wg + (size_t)(i2 * 8) * K + k0, Bsw + i2 * 512);
        __syncthreads();   // drains vmcnt(0): tiles visible

        #pragma unroll
        for (int kk = 0; kk < 2; ++kk) {
            const int ch = (kk * 4 + lg) ^ lm7;      // swizzled 16B chunk
            short8 af[4], bf[NJ];
            #pragma unroll
            for (int i = 0; i < 4; ++i)
                af[i] = *(const short8*)((const char*)As + (wm + i * 16 + lm) * 128 + ch * 16);
            #pragma unroll
            for (int j = 0; j < NJ; ++j)
                bf[j] = *(const short8*)((const char*)Bs + (wn + j * 16 + lm) * 128 + ch * 16);
            #pragma unroll
            for (int i = 0; i < 4; ++i)
                #pragma unroll
                for (int j = 0; j < NJ; ++j)
                    acc[i][j] = __builtin_amdgcn_mfma_f32_16x16x32_bf16(af[i], bf[j], acc[i][j], 0, 0, 0);
        }
        __syncthreads();   // all reads done before next overwrite
    }

    const int sel = n0 >> 10;          // 0=Q 1=K 2=V (block-uniform, MODE 0)
    const float* bias = (MODE == 2) ? bq : (sel == 0) ? bq : (sel == 1) ? bk : bv;

    if constexpr (MODE == 2) {
        const int colb = n0 + wn + lm;
        const int rowb = m0 + wm + lg * 4;
        #pragma unroll
        for (int j = 0; j < NJ; ++j) {
            int col = colb + j * 16;
            float bv_ = bias[col];
            #pragma unroll
            for (int i = 0; i < 4; ++i)
                #pragma unroll
                for (int r = 0; r < 4; ++r)
                    ((float*)out)[(size_t)(rowb + i * 16 + r) * 1024 + col] = acc[i][j][r] + bv_;
        }
    } else {
        // bf16 via wave-private LDS region (72-padded); 16B/lane wide stores.
        short* Es = smem + wave * (64 * 72);
        const int cb = (n0 + wn) & 1023;
        #pragma unroll
        for (int j = 0; j < 4; ++j) {
            float bv_ = bias[cb + j * 16 + lm];
            #pragma unroll
            for (int i = 0; i < 4; ++i)
                #pragma unroll
                for (int r = 0; r < 4; ++r) {
                    float vv = acc[i][j][r] + bv_;
                    if (sel == 0) vv *= 0.1803368867f;   // 0.125*log2(e): exp2-domain Q
                    if (sel < 2)    // Es[s_local][d]
                        Es[(i * 16 + lg * 4 + r) * 72 + j * 16 + lm] = f2bf(vv);
                    else            // V: Es[d][s_local]  (transposed)
                        Es[(j * 16 + lm) * 72 + i * 16 + lg * 4 + r] = f2bf(vv);
                }
        }
        __asm__ __volatile__("s_waitcnt lgkmcnt(0)" ::: "memory");
        short* outQKV = (short*)out;           // [Qh | Kb | Vt]
        const int rl = lane >> 3;
        const int c8 = (lane & 7) * 8;
        const int h  = cb >> 6;
        const int b  = (m0 + wm) >> 11;
        const int bh = (b << 4) + h;
        if (sel < 2) {
            #pragma unroll
            for (int it = 0; it < 8; ++it) {
                int row_l = it * 8 + rl;
                short8 vrow = *(const short8*)&Es[row_l * 72 + c8];
                int s = (m0 + wm + row_l) & 2047;
                *(short8*)(outQKV + (size_t)sel * 4194304 +
                           ((size_t)bh * S_ + s) * DH_ + c8) = vrow;
            }
        } else {
            const int s0 = (m0 + wm) & 2047;
            #pragma unroll
            for (int it = 0; it < 8; ++it) {
                int d_l = it * 8 + rl;
                short8 vrow = *(const short8*)&Es[d_l * 72 + c8];
                *(short8*)(outQKV + (size_t)2 * 4194304 +
                           ((size_t)bh << 17) + ((size_t)d_l << 11) + s0 + c8) = vrow;
            }
        }
    }
}

// ---------------------------------------------------------------------------
// Kernel 3: causal flash attention, LDS-shared K/V tiles, DOUBLE-BUFFERED.
// Block = (bh, q-tile j): 128 q-rows, 4 waves x 32 q-rows; kv pairs of 128,
// npairs = j+1.  Per pair t: issue K-DMA(t+1)->buf^1 + V(t+1) global loads
// (regs) BEFORE compute(t) from buf; write V regs->buf^1 LDS after compute;
// ONE __syncthreads() per pair (drains vmcnt+lgkm).  K swizzle: source-side
// XOR-16B-chunk, LDS dest linear.  V: permuted+swizzled reg-staged layout.
// Grid 512: lo=bid&255 -> xcd=lo&7, j from idx; (j,15-j) co-resident per CU.
// LDS 2 x (16KB K + 16KB V) = 64KB.
// ---------------------------------------------------------------------------
__global__ __launch_bounds__(256, 2) void attn_kernel(
    const short* __restrict__ Q, const short* __restrict__ Kh,
    const short* __restrict__ Vt, short* __restrict__ ctx)
{
    __shared__ __align__(16) short sm[32768];   // 64 KB: 2 x (Kt 8192 | Vp 8192)

    const int t    = threadIdx.x;
    const int lane = t & 63;
    const int w    = t >> 6;
    const int bid  = blockIdx.x;                 // 512 blocks

    const int lo  = bid & 255;
    const int xcd = lo & 7;
    const int idx = lo >> 3;                     // 0..31
    const int bh  = (xcd << 2) + (idx & 3);
    const int jb  = idx >> 2;                    // 0..7
    const int j   = (bid < 256) ? jb : (15 - jb);
    const int q0  = j * 128;
    const int npairs = j + 1;
    const int qr0 = q0 + w * 32;

    const int lm = lane & 15;
    const int lg = lane >> 4;

    const short* Qb = Q  + (size_t)bh * S_ * DH_;
    const short* Kb = Kh + (size_t)bh * S_ * DH_;
    const short* Vb = Vt + ((size_t)bh << 17);

    // ---- staging helpers (identical layouts to R14) ----
    const int rsubK = lane >> 3;                         // 0..7
    const int cswK  = ((lane & 7) ^ rsubK) * 8;          // swizzled src chunk
    const int dV    = w * 16 + (lane >> 2);              // V^T row this thread owns
    const int s3V   = dV & 7;

    auto stageK = [&](int kv0, short* Kt) {
        #pragma unroll
        for (int i2 = 0; i2 < 4; ++i2) {
            const int rb = w * 32 + i2 * 8;
            gl2lds16(Kb + (size_t)(kv0 + rb + rsubK) * 64 + cswK, Kt + rb * 64);
        }
    };
    auto loadV = [&](int kv0, short8* vld) {
        #pragma unroll
        for (int m = 0; m < 4; ++m) {
            const int cm = (lane & 3) + 4 * m;           // 16B piece index
            vld[m] = *(const short8*)(Vb + (size_t)dV * 2048 + kv0 + cm * 8);
        }
    };
    auto writeV = [&](const short8* vld, short* Vp) {
        char* vrow = (char*)Vp + dV * 256;
        #pragma unroll
        for (int m = 0; m < 4; ++m) {
            const int cm = (lane & 3) + 4 * m;
            const int u  = cm >> 3, kk = (cm >> 2) & 1;
            const int q0off = ((cm & 1) << 4) + ((cm >> 1) & 1) * 4;  // shorts
            const int bA = (u * 64 + kk * 32 + q0off) * 2;            // bytes
            const int pA = ((((bA >> 4) ^ s3V) << 4) | (bA & 15));
            const int bB = bA + 16;
            const int pB = ((((bB >> 4) ^ s3V) << 4) | (bB & 15));
            *(short4_t*)(vrow + pA) = __builtin_shufflevector(vld[m], vld[m], 0, 1, 2, 3);
            *(short4_t*)(vrow + pB) = __builtin_shufflevector(vld[m], vld[m], 4, 5, 6, 7);
        }
    };

    // Q as B-operand (pre-scaled by 0.125*log2e at the QKV GEMM):
    short8 qf[2][2];
    #pragma unroll
    for (int t2 = 0; t2 < 2; ++t2)
        #pragma unroll
        for (int kk = 0; kk < 2; ++kk)
            qf[t2][kk] = *(const short8*)(Qb + (size_t)(qr0 + t2 * 16 + lm) * DH_ + kk * 32 + lg * 8);

    float m_i[2] = {-1e30f, -1e30f}, l_i[2] = {0.f, 0.f};
    v4f o[2][4] = {};   // O^T[d = i*16+lg*4+r][q = t2*16+lm]

    // ---- prologue: stage pair 0 into buf0 ----
    short8 vpre[4];
    stageK(0, sm);
    loadV(0, vpre);
    writeV(vpre, sm + 8192);
    __syncthreads();            // drains K DMA (vmcnt) + V writes (lgkm)

    int cur = 0;
    for (int it = 0; it < npairs; ++it) {
        const int kv0 = it * 128;
        const bool dpair = (it == npairs - 1);   // diagonal pair (masked)
        const bool pre   = (it + 1 < npairs);
        short* Kt  = sm + cur * 16384;
        short* Vp  = Kt + 8192;
        short* Ktn = sm + (cur ^ 1) * 16384;
        short* Vpn = Ktn + 8192;

        // ---- prefetch next pair: K DMA into other buf, V into regs ----
        if (pre) {
            stageK(kv0 + 128, Ktn);
            loadV(kv0 + 128, vpre);
        }

        // ---- V^T A-frags from Vp: one swizzled 16B read each ----
        short8 vf[2][2][4];
        #pragma unroll
        for (int u = 0; u < 2; ++u)
            #pragma unroll
            for (int kk = 0; kk < 2; ++kk)
                #pragma unroll
                for (int i = 0; i < 4; ++i) {
                    const int d = i * 16 + lm;
                    const int ch = (u * 8 + kk * 4 + lg) ^ (lm & 7);
                    vf[u][kk][i] = *(const short8*)((const char*)Vp + d * 256 + ch * 16);
                }

        // ---- S^T = K Q^T, both subtiles (32 MFMAs); kf from swizzled Kt ----
        v4f sc[2][2][4] = {};   // [t2][u][jj]
        #pragma unroll
        for (int u = 0; u < 2; ++u) {
            short8 kf[2][4];
            #pragma unroll
            for (int kk = 0; kk < 2; ++kk)
                #pragma unroll
                for (int jj = 0; jj < 4; ++jj) {
                    const int row = u * 64 + jj * 16 + lm;
                    const int ch  = (kk * 4 + lg) ^ (lm & 7);
                    kf[kk][jj] = *(const short8*)((const char*)Kt + row * 128 + ch * 16);
                }
            #pragma unroll
            for (int kk = 0; kk < 2; ++kk)
                #pragma unroll
                for (int t2 = 0; t2 < 2; ++t2)
                    #pragma unroll
                    for (int jj = 0; jj < 4; ++jj)
                        sc[t2][u][jj] = __builtin_amdgcn_mfma_f32_16x16x32_bf16(kf[kk][jj], qf[t2][kk], sc[t2][u][jj], 0, 0, 0);
        }

        // one online-softmax step per t2 over 128 kv (in-lane 32 + 2 shuffles)
        float alpha[2];
        short8 pf[2][2][2];     // [t2][u][kk]
        #pragma unroll
        for (int t2 = 0; t2 < 2; ++t2) {
            float x[2][4][4];
            const int q = qr0 + t2 * 16 + lm;
            #pragma unroll
            for (int u = 0; u < 2; ++u)
                #pragma unroll
                for (int jj = 0; jj < 4; ++jj)
                    #pragma unroll
                    for (int r = 0; r < 4; ++r) {
                        float v = sc[t2][u][jj][r];
                        if (dpair && (kv0 + u * 64 + jj * 16 + lg * 4 + r > q)) v = -1e30f;
                        x[u][jj][r] = v;
                    }
            // tree max over 32 in-lane values
            float m8[8];
            #pragma unroll
            for (int z = 0; z < 8; ++z) {
                const float* xz = x[z >> 2][z & 3];
                m8[z] = fmaxf(fmaxf(xz[0], xz[1]), fmaxf(xz[2], xz[3]));
            }
            float rm = fmaxf(fmaxf(fmaxf(m8[0], m8[1]), fmaxf(m8[2], m8[3])),
                             fmaxf(fmaxf(m8[4], m8[5]), fmaxf(m8[6], m8[7])));
            rm = fmaxf(rm, __shfl_xor(rm, 16, 64));
            rm = fmaxf(rm, __shfl_xor(rm, 32, 64));

            const float mn = fmaxf(m_i[t2], rm);
            alpha[t2] = EXP2(m_i[t2] - mn);
            m_i[t2] = mn;

            // exp2 + tree sum
            float s8[8];
            #pragma unroll
            for (int z = 0; z < 8; ++z) {
                float* xz = x[z >> 2][z & 3];
                xz[0] = EXP2(xz[0] - mn); xz[1] = EXP2(xz[1] - mn);
                xz[2] = EXP2(xz[2] - mn); xz[3] = EXP2(xz[3] - mn);
                s8[z] = (xz[0] + xz[1]) + (xz[2] + xz[3]);
            }
            float rs = ((s8[0] + s8[1]) + (s8[2] + s8[3])) + ((s8[4] + s8[5]) + (s8[6] + s8[7]));
            rs += __shfl_xor(rs, 16, 64);
            rs += __shfl_xor(rs, 32, 64);
            l_i[t2] = l_i[t2] * alpha[t2] + rs;

            // truncating pack: pf[t2][u][kk][jj] = x[u][2kk][jj], [4+jj]=x[u][2kk+1][jj]
            #pragma unroll
            for (int u = 0; u < 2; ++u)
                #pragma unroll
                for (int kk = 0; kk < 2; ++kk) {
                    union { short8 s; uint4 d; } pk;
                    pk.d.x = pack2(x[u][2 * kk][0],     x[u][2 * kk][1]);
                    pk.d.y = pack2(x[u][2 * kk][2],     x[u][2 * kk][3]);
                    pk.d.z = pack2(x[u][2 * kk + 1][0], x[u][2 * kk + 1][1]);
                    pk.d.w = pack2(x[u][2 * kk + 1][2], x[u][2 * kk + 1][3]);
                    pf[t2][u][kk] = pk.s;
                }
        }

        #pragma unroll
        for (int t2 = 0; t2 < 2; ++t2)
            #pragma unroll
            for (int i = 0; i < 4; ++i)
                o[t2][i] *= alpha[t2];

        // O^T += V^T P^T  (32 MFMAs)
        #pragma unroll
        for (int u = 0; u < 2; ++u)
            #pragma unroll
            for (int kk = 0; kk < 2; ++kk)
                #pragma unroll
                for (int t2 = 0; t2 < 2; ++t2)
                    #pragma unroll
                    for (int i = 0; i < 4; ++i)
                        o[t2][i] = __builtin_amdgcn_mfma_f32_16x16x32_bf16(vf[u][kk][i], pf[t2][u][kk], o[t2][i], 0, 0, 0);

        // ---- write prefetched V into the other buffer, then ONE barrier ----
        if (pre) writeV(vpre, Vpn);
        __syncthreads();   // drains this wave's K-DMA (vmcnt) + V ds_writes;
                           // all waves' reads of buf[cur] complete
        cur ^= 1;
    }

    // epilogue: ctx[b*S + q][hd*64 + d] = O/l, 8B stores (all waves)
    const int b = bh >> 4, hd = bh & 15;
    #pragma unroll
    for (int t2 = 0; t2 < 2; ++t2) {
        const float inv = 1.f / l_i[t2];
        const size_t base = ((size_t)(b * S_ + qr0 + t2 * 16 + lm) << 10) + (hd << 6) + lg * 4;
        #pragma unroll
        for (int i = 0; i < 4; ++i) {
            short4_t s4;
            #pragma unroll
            for (int r = 0; r < 4; ++r) s4[r] = f2bf(o[t2][i][r] * inv);
            *(short4_t*)(ctx + base + i * 16) = s4;
        }
    }
}

// ---------------------------------------------------------------------------
extern "C" void kernel_launch(void* const* d_in, const int* in_sizes, int n_in,
                              void* d_out, int out_size, void* d_ws, size_t ws_size,
                              hipStream_t stream) {
    const float* X  = (const float*)d_in[0];
    const float* Wq = (const float*)d_in[2];
    const float* bq = (const float*)d_in[3];
    const float* Wk = (const float*)d_in[4];
    const float* bk = (const float*)d_in[5];
    const float* Wv = (const float*)d_in[6];
    const float* bv = (const float*)d_in[7];
    const float* Wo = (const float*)d_in[8];
    const float* bo = (const float*)d_in[9];
    float* out = (float*)d_out;

    short* ws  = (short*)d_ws;
    short* Xb  = ws;                          // X bf16, 4,194,304
    short* Wb  = Xb + 4194304;                // [Wq|Wk|Wv|Wo] bf16
    short* Qh  = Wb + 4194304;                // [bh][s][64]  (pre-scaled)
    short* Kb  = Qh + 4194304;                // [bh][s][64]
    short* Vt  = Kb + 4194304;                // [bh][64][s] (written by gemm)
    short* Ctx = Vt + 4194304;                // [b*s][1024]

    cast_kernel<<<4096, 256, 0, stream>>>(X, Wq, Wk, Wv, Wo, Xb, Wb);

    // fused QKV projection: flat grid 24*32 = 768, swizzled in-kernel
    gemm_kernel<128, 0><<<768, 256, 0, stream>>>(
        Xb, Wb, bq, bk, bv, Qh, M_, 3 * D_, D_);

    // double-buffered LDS-tile attention: 512 blocks; (j,15-j) per CU
    attn_kernel<<<512, 256, 0, stream>>>(Qh, Kb, Vt, Ctx);

    // output projection: flat grid 16*32 = 512, swizzled in-kernel (2/CU)
    gemm_kernel<64, 2><<<512, 256, 0, stream>>>(
        Ctx, Wb + 3145728, bo, bo, bo, out, M_, D_, D_);
}

// Round 6
// 191.117 us; speedup vs baseline: 1.2431x; 1.2431x over previous
//
#include <hip/hip_runtime.h>

// ---------------------------------------------------------------------------
// MultiHeadAttention: B=2, S=2048, H=16, Dh=64, D=1024, causal mask, fp32 I/O.
// R16: attention = R14's verified single-buffer schedule, re-partitioned to
//      8 waves x 16 q-rows per 128-row block (512 threads).  R15's reg-held
//      V-prefetch spilled (+32MB scratch, 49->92us) -> reverted.  The 8-wave
//      split halves per-wave fragment state (no t2 dim) and doubles resident
//      waves to 4/SIMD so barrier + softmax-chain stalls of one block hide
//      under the other block's compute.  Layouts/swizzles/masking unchanged.
//      GEMMs unchanged (R14 conflict-free swizzled staging, verified).
// ---------------------------------------------------------------------------

#define B_   2
#define S_   2048
#define H_   16
#define DH_  64
#define D_   1024
#define M_   (B_ * S_)          // 4096 rows

typedef __attribute__((ext_vector_type(8))) short short8;
typedef __attribute__((ext_vector_type(4))) short short4_t;
typedef float v4f __attribute__((ext_vector_type(4)));

__device__ __forceinline__ short f2bf(float f) {
    union { float f; unsigned u; } v; v.f = f;
    unsigned r = v.u + 0x7fffu + ((v.u >> 16) & 1u);  // round-to-nearest-even
    return (short)(r >> 16);
}

#if __has_builtin(__builtin_amdgcn_exp2f)
#define EXP2(x) __builtin_amdgcn_exp2f(x)
#else
#define EXP2(x) exp2f(x)
#endif

// pack two f32 -> dword of two truncated bf16 (low short = a, high = b)
__device__ __forceinline__ unsigned pack2(float a, float b) {
    return (__float_as_uint(a) >> 16) | (__float_as_uint(b) & 0xFFFF0000u);
}

// async 16B/lane global -> LDS DMA (lane l deposits at lds + l*16)
__device__ __forceinline__ void gl2lds16(const short* g, short* l) {
    __builtin_amdgcn_global_load_lds(
        (const __attribute__((address_space(1))) unsigned int*)g,
        (__attribute__((address_space(3))) unsigned int*)l,
        16, 0, 0);
}

// ---------------------------------------------------------------------------
// Kernel 1: cast X and Wq,Wk,Wv,Wo fp32 -> bf16.  8 elems/thread, 16B stores.
// ---------------------------------------------------------------------------
__global__ __launch_bounds__(256) void cast_kernel(
    const float* __restrict__ X,
    const float* __restrict__ Wq, const float* __restrict__ Wk,
    const float* __restrict__ Wv, const float* __restrict__ Wo,
    short* __restrict__ Xb, short* __restrict__ Wb)
{
    const int NX8 = (M_ * D_) / 8;      // 524,288
    const int NW8 = (D_ * D_) / 8;      // 131,072
    int idx = blockIdx.x * 256 + threadIdx.x;   // 1,048,576 threads

    const float* src; short* dst; int off;
    if (idx < NX8) { src = X; dst = Xb; off = idx; }
    else {
        int r = idx - NX8;
        int sel = r >> 17;
        int o = r & (NW8 - 1);
        src = (sel == 0) ? Wq : (sel == 1) ? Wk : (sel == 2) ? Wv : Wo;
        dst = Wb + sel * (D_ * D_);
        off = o;
    }
    float4 f0 = ((const float4*)src)[off * 2];
    float4 f1 = ((const float4*)src)[off * 2 + 1];
    short8 s;
    s[0] = f2bf(f0.x); s[1] = f2bf(f0.y); s[2] = f2bf(f0.z); s[3] = f2bf(f0.w);
    s[4] = f2bf(f1.x); s[5] = f2bf(f1.y); s[6] = f2bf(f1.z); s[7] = f2bf(f1.w);
    *(short8*)(dst + (size_t)off * 8) = s;
}

// ---------------------------------------------------------------------------
// Kernel 2: C = A(bf16,[M,K]) @ W(bf16,[N,K])^T + bias.  BM=128, BK=64.
// m97 staging into XOR-16B-chunk-SWIZZLED LDS tiles: gl2lds dest linear,
// global source chunk = (lane&7)^rsub; fragment read chunk = (kk*4+lg)^(lm&7)
// MODE 0 (BN=128): fused QKV, N=3072.  Q,K natural [bh][s][64]; V -> Vt
//                  [bh][64][s] via transposed LDS epilogue, 16B/lane stores.
//                  Q is PRE-SCALED by 0.125*log2(e) (attn exp2-domain fold).
// MODE 2 (BN=64):  fp32 out [M,1024] (final projection), 512 blocks (2/CU).
// XCD-aware flat-grid swizzle: xcd=bid&7 owns 4 m-rows.
// ---------------------------------------------------------------------------
template<int BN, int MODE>
__global__ __launch_bounds__(256) void gemm_kernel(
    const short* __restrict__ A, const short* __restrict__ W,
    const float* __restrict__ bq, const float* __restrict__ bk,
    const float* __restrict__ bv, void* __restrict__ out,
    int M, int N, int K)
{
    constexpr int SM = (MODE == 0) ? 18432 : (8192 + BN * 64);
    __shared__ __align__(16) short smem[SM];
    short* As = smem;                                  // [128][64] swizzled
    short* Bs = smem + 8192;                           // [BN][64]  swizzled

    const int t    = threadIdx.x;
    const int lane = t & 63;
    const int wave = t >> 6;

    const int bid = blockIdx.x;
    const int by  = ((bid & 7) << 2) + ((bid >> 3) & 3);
    const int bx  = bid >> 5;
    const int m0 = by * 128;
    const int n0 = bx * BN;

    const int wm = (wave >> 1) * 64;
    const int wn = (wave & 1) * (BN / 2);
    constexpr int NJ  = BN / 32;       // acc cols per wave (4 or 2)
    constexpr int BIT = BN / 32;       // B staging insts per wave

    v4f acc[4][NJ] = {};

    // staging: inst i2 covers 8 rows; lane l -> row +(l>>3),
    // SOURCE chunk ((l&7)^(l>>3))*8 shorts  (inverse of the read swizzle)
    const int rsub = lane >> 3;
    const int csw  = ((lane & 7) ^ rsub) * 8;
    const short* Ag = A + (size_t)(m0 + wave * 32 + rsub) * K + csw;
    const short* Wg = W + (size_t)(n0 + wave * (BN / 4) + rsub) * K + csw;
    short* Asw = As + (wave * 32) * 64;
    short* Bsw = Bs + (wave * (BN / 4)) * 64;

    const int lm = lane & 15;
    const int lg = lane >> 4;
    const int lm7 = lm & 7;

    for (int k0 = 0; k0 < K; k0 += 64) {
        #pragma unroll
        for (int i2 = 0; i2 < 4; ++i2)
            gl2lds16(Ag + (size_t)(i2 * 8) * K + k0, Asw + i2 * 512);
        #pragma unroll
        for (int i2 = 0; i2 < BIT; ++i2)
            gl2lds16(Wg + (size_t)(i2 * 8) * K + k0, Bsw + i2 * 512);
        __syncthreads();   // drains vmcnt(0): tiles visible

        #pragma unroll
        for (int kk = 0; kk < 2; ++kk) {
            const int ch = (kk * 4 + lg) ^ lm7;      // swizzled 16B chunk
            short8 af[4], bf[NJ];
            #pragma unroll
            for (int i = 0; i < 4; ++i)
                af[i] = *(const short8*)((const char*)As + (wm + i * 16 + lm) * 128 + ch * 16);
            #pragma unroll
            for (int j = 0; j < NJ; ++j)
                bf[j] = *(const short8*)((const char*)Bs + (wn + j * 16 + lm) * 128 + ch * 16);
            #pragma unroll
            for (int i = 0; i < 4; ++i)
                #pragma unroll
                for (int j = 0; j < NJ; ++j)
                    acc[i][j] = __builtin_amdgcn_mfma_f32_16x16x32_bf16(af[i], bf[j], acc[i][j], 0, 0, 0);
        }
        __syncthreads();   // all reads done before next overwrite
    }

    const int sel = n0 >> 10;          // 0=Q 1=K 2=V (block-uniform, MODE 0)
    const float* bias = (MODE == 2) ? bq : (sel == 0) ? bq : (sel == 1) ? bk : bv;

    if constexpr (MODE == 2) {
        const int colb = n0 + wn + lm;
        const int rowb = m0 + wm + lg * 4;
        #pragma unroll
        for (int j = 0; j < NJ; ++j) {
            int col = colb + j * 16;
            float bv_ = bias[col];
            #pragma unroll
            for (int i = 0; i < 4; ++i)
                #pragma unroll
                for (int r = 0; r < 4; ++r)
                    ((float*)out)[(size_t)(rowb + i * 16 + r) * 1024 + col] = acc[i][j][r] + bv_;
        }
    } else {
        // bf16 via wave-private LDS region (72-padded); 16B/lane wide stores.
        short* Es = smem + wave * (64 * 72);
        const int cb = (n0 + wn) & 1023;
        #pragma unroll
        for (int j = 0; j < 4; ++j) {
            float bv_ = bias[cb + j * 16 + lm];
            #pragma unroll
            for (int i = 0; i < 4; ++i)
                #pragma unroll
                for (int r = 0; r < 4; ++r) {
                    float vv = acc[i][j][r] + bv_;
                    if (sel == 0) vv *= 0.1803368867f;   // 0.125*log2(e): exp2-domain Q
                    if (sel < 2)    // Es[s_local][d]
                        Es[(i * 16 + lg * 4 + r) * 72 + j * 16 + lm] = f2bf(vv);
                    else            // V: Es[d][s_local]  (transposed)
                        Es[(j * 16 + lm) * 72 + i * 16 + lg * 4 + r] = f2bf(vv);
                }
        }
        __asm__ __volatile__("s_waitcnt lgkmcnt(0)" ::: "memory");
        short* outQKV = (short*)out;           // [Qh | Kb | Vt]
        const int rl = lane >> 3;
        const int c8 = (lane & 7) * 8;
        const int h  = cb >> 6;
        const int b  = (m0 + wm) >> 11;
        const int bh = (b << 4) + h;
        if (sel < 2) {
            #pragma unroll
            for (int it = 0; it < 8; ++it) {
                int row_l = it * 8 + rl;
                short8 vrow = *(const short8*)&Es[row_l * 72 + c8];
                int s = (m0 + wm + row_l) & 2047;
                *(short8*)(outQKV + (size_t)sel * 4194304 +
                           ((size_t)bh * S_ + s) * DH_ + c8) = vrow;
            }
        } else {
            const int s0 = (m0 + wm) & 2047;
            #pragma unroll
            for (int it = 0; it < 8; ++it) {
                int d_l = it * 8 + rl;
                short8 vrow = *(const short8*)&Es[d_l * 72 + c8];
                *(short8*)(outQKV + (size_t)2 * 4194304 +
                           ((size_t)bh << 17) + ((size_t)d_l << 11) + s0 + c8) = vrow;
            }
        }
    }
}

// ---------------------------------------------------------------------------
// Kernel 3: causal flash attention, LDS-shared K/V tiles, 8 waves x 16 q-rows.
// Block = (bh, q-tile j): 128 q-rows, 512 threads; kv pairs of 128,
// npairs = j+1 (diagonal pair masked).  Single-buffer, 2 barriers/pair
// (R14-verified schedule).  K tile [128][64]: global_load_lds with source-
// side XOR-16B-chunk swizzle (LDS dest linear).  V^T tile [64][128]:
// reg-staged into permuted+swizzled LDS; PV A-frags = single ds_read_b128.
// 2 blocks/CU x 8 waves = 16 waves/CU = 4/SIMD (R14 was 2/SIMD).
// Grid 512: lo=bid&255 -> xcd=lo&7, j from idx; (j,15-j) co-resident per CU.
// ---------------------------------------------------------------------------
__global__ __launch_bounds__(512, 2) void attn_kernel(
    const short* __restrict__ Q, const short* __restrict__ Kh,
    const short* __restrict__ Vt, short* __restrict__ ctx)
{
    __shared__ __align__(16) short sm[16384];   // 32 KB
    short* Kt = sm;            // [128][64] bf16, 16B-chunk swizzled
    short* Vp = sm + 8192;     // [64][128] bf16, permuted k-slots + swizzled

    const int t    = threadIdx.x;
    const int lane = t & 63;
    const int w    = t >> 6;                     // 0..7
    const int bid  = blockIdx.x;                 // 512 blocks

    const int lo  = bid & 255;
    const int xcd = lo & 7;
    const int idx = lo >> 3;                     // 0..31
    const int bh  = (xcd << 2) + (idx & 3);
    const int jb  = idx >> 2;                    // 0..7
    const int j   = (bid < 256) ? jb : (15 - jb);
    const int q0  = j * 128;
    const int npairs = j + 1;
    const int qr0 = q0 + w * 16;                 // this wave's 16 q-rows

    const int lm = lane & 15;
    const int lg = lane >> 4;

    const short* Qb = Q  + (size_t)bh * S_ * DH_;
    const short* Kb = Kh + (size_t)bh * S_ * DH_;
    const short* Vb = Vt + ((size_t)bh << 17);

    // Q as B-operand (pre-scaled by 0.125*log2e at the QKV GEMM):
    // B[n=q=qr0+lm][k=kk*32+lg*8+s]
    short8 qf[2];
    #pragma unroll
    for (int kk = 0; kk < 2; ++kk)
        qf[kk] = *(const short8*)(Qb + (size_t)(qr0 + lm) * DH_ + kk * 32 + lg * 8);

    float m_i = -1e30f, l_i = 0.f;
    v4f o[4] = {};   // O^T[d = i*16+lg*4+r][q = lm]

    for (int it = 0; it < npairs; ++it) {
        const int kv0 = it * 128;
        const bool dpair = (it == npairs - 1);   // diagonal pair (masked)

        // ---- stage K rows [kv0, kv0+128) x 64d into Kt (wave w: 16 rows) ---
        {
            const int rsub = lane >> 3;                      // 0..7
            const int csw  = ((lane & 7) ^ rsub) * 8;        // swizzled src chunk (shorts)
            #pragma unroll
            for (int i2 = 0; i2 < 2; ++i2) {
                const int rb = w * 16 + i2 * 8;
                gl2lds16(Kb + (size_t)(kv0 + rb + rsub) * 64 + csw, Kt + rb * 64);
            }
        }
        // ---- stage V^T rows [w*8, w*8+8) x 128kv into Vp (perm+swz) ----
        {
            const int d  = w * 8 + (lane >> 3);              // V^T row
            const int s3 = d & 7;
            short8 vld[2];
            #pragma unroll
            for (int m = 0; m < 2; ++m) {
                const int cm = (lane & 7) + 8 * m;           // 16B piece index
                vld[m] = *(const short8*)(Vb + (size_t)d * 2048 + kv0 + cm * 8);
            }
            char* vrow = (char*)Vp + d * 256;
            #pragma unroll
            for (int m = 0; m < 2; ++m) {
                const int cm = (lane & 7) + 8 * m;
                const int u  = cm >> 3, kk = (cm >> 2) & 1;
                const int q0off = ((cm & 1) << 4) + ((cm >> 1) & 1) * 4;  // shorts
                const int bA = (u * 64 + kk * 32 + q0off) * 2;            // bytes
                const int pA = ((((bA >> 4) ^ s3) << 4) | (bA & 15));
                const int bB = bA + 16;
                const int pB = ((((bB >> 4) ^ s3) << 4) | (bB & 15));
                *(short4_t*)(vrow + pA) = __builtin_shufflevector(vld[m], vld[m], 0, 1, 2, 3);
                *(short4_t*)(vrow + pB) = __builtin_shufflevector(vld[m], vld[m], 4, 5, 6, 7);
            }
        }
        __syncthreads();   // drains vmcnt+lgkm: K (DMA) and V (writes) visible

        // ---- V^T A-frags from Vp: one swizzled 16B read each ----
        short8 vf[2][2][4];
        #pragma unroll
        for (int u = 0; u < 2; ++u)
            #pragma unroll
            for (int kk = 0; kk < 2; ++kk)
                #pragma unroll
                for (int i = 0; i < 4; ++i) {
                    const int d = i * 16 + lm;
                    const int ch = (u * 8 + kk * 4 + lg) ^ (lm & 7);
                    vf[u][kk][i] = *(const short8*)((const char*)Vp + d * 256 + ch * 16);
                }

        // ---- S^T = K Q^T, both subtiles (16 MFMAs); kf from swizzled Kt ----
        v4f sc[2][4] = {};   // [u][jj]
        #pragma unroll
        for (int u = 0; u < 2; ++u) {
            short8 kf[2][4];
            #pragma unroll
            for (int kk = 0; kk < 2; ++kk)
                #pragma unroll
                for (int jj = 0; jj < 4; ++jj) {
                    const int row = u * 64 + jj * 16 + lm;
                    const int ch  = (kk * 4 + lg) ^ (lm & 7);
                    kf[kk][jj] = *(const short8*)((const char*)Kt + row * 128 + ch * 16);
                }
            #pragma unroll
            for (int kk = 0; kk < 2; ++kk)
                #pragma unroll
                for (int jj = 0; jj < 4; ++jj)
                    sc[u][jj] = __builtin_amdgcn_mfma_f32_16x16x32_bf16(kf[kk][jj], qf[kk], sc[u][jj], 0, 0, 0);
        }

        // one online-softmax step over 128 kv (in-lane 32 + 2 shuffles)
        float alpha;
        short8 pf[2][2];     // [u][kk]
        {
            float x[2][4][4];
            const int q = qr0 + lm;
            #pragma unroll
            for (int u = 0; u < 2; ++u)
                #pragma unroll
                for (int jj = 0; jj < 4; ++jj)
                    #pragma unroll
                    for (int r = 0; r < 4; ++r) {
                        float v = sc[u][jj][r];
                        if (dpair && (kv0 + u * 64 + jj * 16 + lg * 4 + r > q)) v = -1e30f;
                        x[u][jj][r] = v;
                    }
            // tree max over 32 in-lane values
            float m8[8];
            #pragma unroll
            for (int z = 0; z < 8; ++z) {
                const float* xz = x[z >> 2][z & 3];
                m8[z] = fmaxf(fmaxf(xz[0], xz[1]), fmaxf(xz[2], xz[3]));
            }
            float rm = fmaxf(fmaxf(fmaxf(m8[0], m8[1]), fmaxf(m8[2], m8[3])),
                             fmaxf(fmaxf(m8[4], m8[5]), fmaxf(m8[6], m8[7])));
            rm = fmaxf(rm, __shfl_xor(rm, 16, 64));
            rm = fmaxf(rm, __shfl_xor(rm, 32, 64));

            const float mn = fmaxf(m_i, rm);
            alpha = EXP2(m_i - mn);
            m_i = mn;

            // exp2 + tree sum
            float s8[8];
            #pragma unroll
            for (int z = 0; z < 8; ++z) {
                float* xz = x[z >> 2][z & 3];
                xz[0] = EXP2(xz[0] - mn); xz[1] = EXP2(xz[1] - mn);
                xz[2] = EXP2(xz[2] - mn); xz[3] = EXP2(xz[3] - mn);
                s8[z] = (xz[0] + xz[1]) + (xz[2] + xz[3]);
            }
            float rs = ((s8[0] + s8[1]) + (s8[2] + s8[3])) + ((s8[4] + s8[5]) + (s8[6] + s8[7]));
            rs += __shfl_xor(rs, 16, 64);
            rs += __shfl_xor(rs, 32, 64);
            l_i = l_i * alpha + rs;

            // truncating pack: pf[u][kk][jj] = x[u][2kk][jj], [4+jj]=x[u][2kk+1][jj]
            #pragma unroll
            for (int u = 0; u < 2; ++u)
                #pragma unroll
                for (int kk = 0; kk < 2; ++kk) {
                    union { short8 s; uint4 d; } pk;
                    pk.d.x = pack2(x[u][2 * kk][0],     x[u][2 * kk][1]);
                    pk.d.y = pack2(x[u][2 * kk][2],     x[u][2 * kk][3]);
                    pk.d.z = pack2(x[u][2 * kk + 1][0], x[u][2 * kk + 1][1]);
                    pk.d.w = pack2(x[u][2 * kk + 1][2], x[u][2 * kk + 1][3]);
                    pf[u][kk] = pk.s;
                }
        }

        #pragma unroll
        for (int i = 0; i < 4; ++i)
            o[i] *= alpha;

        // O^T += V^T P^T  (16 MFMAs)
        #pragma unroll
        for (int u = 0; u < 2; ++u)
            #pragma unroll
            for (int kk = 0; kk < 2; ++kk)
                #pragma unroll
                for (int i = 0; i < 4; ++i)
                    o[i] = __builtin_amdgcn_mfma_f32_16x16x32_bf16(vf[u][kk][i], pf[u][kk], o[i], 0, 0, 0);

        __syncthreads();   // all LDS reads done before next pair's staging
    }

    // epilogue: ctx[b*S + q][hd*64 + d] = O/l, 8B stores (all waves)
    const int b = bh >> 4, hd = bh & 15;
    {
        const float inv = 1.f / l_i;
        const size_t base = ((size_t)(b * S_ + qr0 + lm) << 10) + (hd << 6) + lg * 4;
        #pragma unroll
        for (int i = 0; i < 4; ++i) {
            short4_t s4;
            #pragma unroll
            for (int r = 0; r < 4; ++r) s4[r] = f2bf(o[i][r] * inv);
            *(short4_t*)(ctx + base + i * 16) = s4;
        }
    }
}

// ---------------------------------------------------------------------------
extern "C" void kernel_launch(void* const* d_in, const int* in_sizes, int n_in,
                              void* d_out, int out_size, void* d_ws, size_t ws_size,
                              hipStream_t stream) {
    const float* X  = (const float*)d_in[0];
    const float* Wq = (const float*)d_in[2];
    const float* bq = (const float*)d_in[3];
    const float* Wk = (const float*)d_in[4];
    const float* bk = (const float*)d_in[5];
    const float* Wv = (const float*)d_in[6];
    const float* bv = (const float*)d_in[7];
    const float* Wo = (const float*)d_in[8];
    const float* bo = (const float*)d_in[9];
    float* out = (float*)d_out;

    short* ws  = (short*)d_ws;
    short* Xb  = ws;                          // X bf16, 4,194,304
    short* Wb  = Xb + 4194304;                // [Wq|Wk|Wv|Wo] bf16
    short* Qh  = Wb + 4194304;                // [bh][s][64]  (pre-scaled)
    short* Kb  = Qh + 4194304;                // [bh][s][64]
    short* Vt  = Kb + 4194304;                // [bh][64][s] (written by gemm)
    short* Ctx = Vt + 4194304;                // [b*s][1024]

    cast_kernel<<<4096, 256, 0, stream>>>(X, Wq, Wk, Wv, Wo, Xb, Wb);

    // fused QKV projection: flat grid 24*32 = 768, swizzled in-kernel
    gemm_kernel<128, 0><<<768, 256, 0, stream>>>(
        Xb, Wb, bq, bk, bv, Qh, M_, 3 * D_, D_);

    // 8-wave LDS-tile attention: 512 blocks x 512 threads; (j,15-j) per CU
    attn_kernel<<<512, 512, 0, stream>>>(Qh, Kb, Vt, Ctx);

    // output projection: flat grid 16*32 = 512, swizzled in-kernel (2/CU)
    gemm_kernel<64, 2><<<512, 256, 0, stream>>>(
        Ctx, Wb + 3145728, bo, bo, bo, out, M_, D_, D_);
}

// Round 7
// 188.509 us; speedup vs baseline: 1.2603x; 1.0138x over previous
//
#include <hip/hip_runtime.h>

// ---------------------------------------------------------------------------
// MultiHeadAttention: B=2, S=2048, H=16, Dh=64, D=1024, causal mask, fp32 I/O.
// R17: attention = R16's 8-wave x 16-q-row partition + R15's double-buffered
//      one-barrier pipeline.  R15 failed from VGPR spill at the 4-wave shape
//      (base 104 + 16-reg V prefetch -> 128 cap + 32MB scratch); R16's 8-wave
//      shape has base 84 and V prefetch of only 8 VGPR -> fits.  Per pair:
//      issue K-DMA(t+1) into idle buffer + V(t+1) global loads (regs) BEFORE
//      compute(t); write V regs->LDS after compute; ONE __syncthreads()/pair.
//      Compute/swizzles/masking byte-identical to R16 (verified).
//      GEMMs unchanged (R14 conflict-free swizzled staging, verified).
// ---------------------------------------------------------------------------

#define B_   2
#define S_   2048
#define H_   16
#define DH_  64
#define D_   1024
#define M_   (B_ * S_)          // 4096 rows

typedef __attribute__((ext_vector_type(8))) short short8;
typedef __attribute__((ext_vector_type(4))) short short4_t;
typedef float v4f __attribute__((ext_vector_type(4)));

__device__ __forceinline__ short f2bf(float f) {
    union { float f; unsigned u; } v; v.f = f;
    unsigned r = v.u + 0x7fffu + ((v.u >> 16) & 1u);  // round-to-nearest-even
    return (short)(r >> 16);
}

#if __has_builtin(__builtin_amdgcn_exp2f)
#define EXP2(x) __builtin_amdgcn_exp2f(x)
#else
#define EXP2(x) exp2f(x)
#endif

// pack two f32 -> dword of two truncated bf16 (low short = a, high = b)
__device__ __forceinline__ unsigned pack2(float a, float b) {
    return (__float_as_uint(a) >> 16) | (__float_as_uint(b) & 0xFFFF0000u);
}

// async 16B/lane global -> LDS DMA (lane l deposits at lds + l*16)
__device__ __forceinline__ void gl2lds16(const short* g, short* l) {
    __builtin_amdgcn_global_load_lds(
        (const __attribute__((address_space(1))) unsigned int*)g,
        (__attribute__((address_space(3))) unsigned int*)l,
        16, 0, 0);
}

// ---------------------------------------------------------------------------
// Kernel 1: cast X and Wq,Wk,Wv,Wo fp32 -> bf16.  8 elems/thread, 16B stores.
// ---------------------------------------------------------------------------
__global__ __launch_bounds__(256) void cast_kernel(
    const float* __restrict__ X,
    const float* __restrict__ Wq, const float* __restrict__ Wk,
    const float* __restrict__ Wv, const float* __restrict__ Wo,
    short* __restrict__ Xb, short* __restrict__ Wb)
{
    const int NX8 = (M_ * D_) / 8;      // 524,288
    const int NW8 = (D_ * D_) / 8;      // 131,072
    int idx = blockIdx.x * 256 + threadIdx.x;   // 1,048,576 threads

    const float* src; short* dst; int off;
    if (idx < NX8) { src = X; dst = Xb; off = idx; }
    else {
        int r = idx - NX8;
        int sel = r >> 17;
        int o = r & (NW8 - 1);
        src = (sel == 0) ? Wq : (sel == 1) ? Wk : (sel == 2) ? Wv : Wo;
        dst = Wb + sel * (D_ * D_);
        off = o;
    }
    float4 f0 = ((const float4*)src)[off * 2];
    float4 f1 = ((const float4*)src)[off * 2 + 1];
    short8 s;
    s[0] = f2bf(f0.x); s[1] = f2bf(f0.y); s[2] = f2bf(f0.z); s[3] = f2bf(f0.w);
    s[4] = f2bf(f1.x); s[5] = f2bf(f1.y); s[6] = f2bf(f1.z); s[7] = f2bf(f1.w);
    *(short8*)(dst + (size_t)off * 8) = s;
}

// ---------------------------------------------------------------------------
// Kernel 2: C = A(bf16,[M,K]) @ W(bf16,[N,K])^T + bias.  BM=128, BK=64.
// m97 staging into XOR-16B-chunk-SWIZZLED LDS tiles: gl2lds dest linear,
// global source chunk = (lane&7)^rsub; fragment read chunk = (kk*4+lg)^(lm&7)
// MODE 0 (BN=128): fused QKV, N=3072.  Q,K natural [bh][s][64]; V -> Vt
//                  [bh][64][s] via transposed LDS epilogue, 16B/lane stores.
//                  Q is PRE-SCALED by 0.125*log2(e) (attn exp2-domain fold).
// MODE 2 (BN=64):  fp32 out [M,1024] (final projection), 512 blocks (2/CU).
// XCD-aware flat-grid swizzle: xcd=bid&7 owns 4 m-rows.
// ---------------------------------------------------------------------------
template<int BN, int MODE>
__global__ __launch_bounds__(256) void gemm_kernel(
    const short* __restrict__ A, const short* __restrict__ W,
    const float* __restrict__ bq, const float* __restrict__ bk,
    const float* __restrict__ bv, void* __restrict__ out,
    int M, int N, int K)
{
    constexpr int SM = (MODE == 0) ? 18432 : (8192 + BN * 64);
    __shared__ __align__(16) short smem[SM];
    short* As = smem;                                  // [128][64] swizzled
    short* Bs = smem + 8192;                           // [BN][64]  swizzled

    const int t    = threadIdx.x;
    const int lane = t & 63;
    const int wave = t >> 6;

    const int bid = blockIdx.x;
    const int by  = ((bid & 7) << 2) + ((bid >> 3) & 3);
    const int bx  = bid >> 5;
    const int m0 = by * 128;
    const int n0 = bx * BN;

    const int wm = (wave >> 1) * 64;
    const int wn = (wave & 1) * (BN / 2);
    constexpr int NJ  = BN / 32;       // acc cols per wave (4 or 2)
    constexpr int BIT = BN / 32;       // B staging insts per wave

    v4f acc[4][NJ] = {};

    // staging: inst i2 covers 8 rows; lane l -> row +(l>>3),
    // SOURCE chunk ((l&7)^(l>>3))*8 shorts  (inverse of the read swizzle)
    const int rsub = lane >> 3;
    const int csw  = ((lane & 7) ^ rsub) * 8;
    const short* Ag = A + (size_t)(m0 + wave * 32 + rsub) * K + csw;
    const short* Wg = W + (size_t)(n0 + wave * (BN / 4) + rsub) * K + csw;
    short* Asw = As + (wave * 32) * 64;
    short* Bsw = Bs + (wave * (BN / 4)) * 64;

    const int lm = lane & 15;
    const int lg = lane >> 4;
    const int lm7 = lm & 7;

    for (int k0 = 0; k0 < K; k0 += 64) {
        #pragma unroll
        for (int i2 = 0; i2 < 4; ++i2)
            gl2lds16(Ag + (size_t)(i2 * 8) * K + k0, Asw + i2 * 512);
        #pragma unroll
        for (int i2 = 0; i2 < BIT; ++i2)
            gl2lds16(Wg + (size_t)(i2 * 8) * K + k0, Bsw + i2 * 512);
        __syncthreads();   // drains vmcnt(0): tiles visible

        #pragma unroll
        for (int kk = 0; kk < 2; ++kk) {
            const int ch = (kk * 4 + lg) ^ lm7;      // swizzled 16B chunk
            short8 af[4], bf[NJ];
            #pragma unroll
            for (int i = 0; i < 4; ++i)
                af[i] = *(const short8*)((const char*)As + (wm + i * 16 + lm) * 128 + ch * 16);
            #pragma unroll
            for (int j = 0; j < NJ; ++j)
                bf[j] = *(const short8*)((const char*)Bs + (wn + j * 16 + lm) * 128 + ch * 16);
            #pragma unroll
            for (int i = 0; i < 4; ++i)
                #pragma unroll
                for (int j = 0; j < NJ; ++j)
                    acc[i][j] = __builtin_amdgcn_mfma_f32_16x16x32_bf16(af[i], bf[j], acc[i][j], 0, 0, 0);
        }
        __syncthreads();   // all reads done before next overwrite
    }

    const int sel = n0 >> 10;          // 0=Q 1=K 2=V (block-uniform, MODE 0)
    const float* bias = (MODE == 2) ? bq : (sel == 0) ? bq : (sel == 1) ? bk : bv;

    if constexpr (MODE == 2) {
        const int colb = n0 + wn + lm;
        const int rowb = m0 + wm + lg * 4;
        #pragma unroll
        for (int j = 0; j < NJ; ++j) {
            int col = colb + j * 16;
            float bv_ = bias[col];
            #pragma unroll
            for (int i = 0; i < 4; ++i)
                #pragma unroll
                for (int r = 0; r < 4; ++r)
                    ((float*)out)[(size_t)(rowb + i * 16 + r) * 1024 + col] = acc[i][j][r] + bv_;
        }
    } else {
        // bf16 via wave-private LDS region (72-padded); 16B/lane wide stores.
        short* Es = smem + wave * (64 * 72);
        const int cb = (n0 + wn) & 1023;
        #pragma unroll
        for (int j = 0; j < 4; ++j) {
            float bv_ = bias[cb + j * 16 + lm];
            #pragma unroll
            for (int i = 0; i < 4; ++i)
                #pragma unroll
                for (int r = 0; r < 4; ++r) {
                    float vv = acc[i][j][r] + bv_;
                    if (sel == 0) vv *= 0.1803368867f;   // 0.125*log2(e): exp2-domain Q
                    if (sel < 2)    // Es[s_local][d]
                        Es[(i * 16 + lg * 4 + r) * 72 + j * 16 + lm] = f2bf(vv);
                    else            // V: Es[d][s_local]  (transposed)
                        Es[(j * 16 + lm) * 72 + i * 16 + lg * 4 + r] = f2bf(vv);
                }
        }
        __asm__ __volatile__("s_waitcnt lgkmcnt(0)" ::: "memory");
        short* outQKV = (short*)out;           // [Qh | Kb | Vt]
        const int rl = lane >> 3;
        const int c8 = (lane & 7) * 8;
        const int h  = cb >> 6;
        const int b  = (m0 + wm) >> 11;
        const int bh = (b << 4) + h;
        if (sel < 2) {
            #pragma unroll
            for (int it = 0; it < 8; ++it) {
                int row_l = it * 8 + rl;
                short8 vrow = *(const short8*)&Es[row_l * 72 + c8];
                int s = (m0 + wm + row_l) & 2047;
                *(short8*)(outQKV + (size_t)sel * 4194304 +
                           ((size_t)bh * S_ + s) * DH_ + c8) = vrow;
            }
        } else {
            const int s0 = (m0 + wm) & 2047;
            #pragma unroll
            for (int it = 0; it < 8; ++it) {
                int d_l = it * 8 + rl;
                short8 vrow = *(const short8*)&Es[d_l * 72 + c8];
                *(short8*)(outQKV + (size_t)2 * 4194304 +
                           ((size_t)bh << 17) + ((size_t)d_l << 11) + s0 + c8) = vrow;
            }
        }
    }
}

// ---------------------------------------------------------------------------
// Kernel 3: causal flash attention, 8 waves x 16 q-rows, DOUBLE-BUFFERED.
// Block = (bh, q-tile j): 128 q-rows, 512 threads; kv pairs of 128,
// npairs = j+1 (diagonal pair masked).  Per pair t: issue K-DMA(t+1) into
// the idle buffer + V(t+1) global loads (8 VGPR) BEFORE compute(t); write V
// regs->LDS after compute; ONE __syncthreads()/pair (drains vmcnt+lgkm).
// K tile [128][64]: global_load_lds, source-side XOR-16B-chunk swizzle.
// V^T tile [64][128]: reg-staged into permuted+swizzled LDS.
// LDS 2 x (8KB K + 8KB V)*2B = 64KB; 2 blocks/CU -> 16 waves/CU = 4/SIMD.
// Grid 512: lo=bid&255 -> xcd=lo&7, j from idx; (j,15-j) co-resident per CU.
// ---------------------------------------------------------------------------
__global__ __launch_bounds__(512, 2) void attn_kernel(
    const short* __restrict__ Q, const short* __restrict__ Kh,
    const short* __restrict__ Vt, short* __restrict__ ctx)
{
    __shared__ __align__(16) short sm[32768];   // 64 KB: 2 x (Kt 8192 | Vp 8192)

    const int t    = threadIdx.x;
    const int lane = t & 63;
    const int w    = t >> 6;                     // 0..7
    const int bid  = blockIdx.x;                 // 512 blocks

    const int lo  = bid & 255;
    const int xcd = lo & 7;
    const int idx = lo >> 3;                     // 0..31
    const int bh  = (xcd << 2) + (idx & 3);
    const int jb  = idx >> 2;                    // 0..7
    const int j   = (bid < 256) ? jb : (15 - jb);
    const int q0  = j * 128;
    const int npairs = j + 1;
    const int qr0 = q0 + w * 16;                 // this wave's 16 q-rows

    const int lm = lane & 15;
    const int lg = lane >> 4;

    const short* Qb = Q  + (size_t)bh * S_ * DH_;
    const short* Kb = Kh + (size_t)bh * S_ * DH_;
    const short* Vb = Vt + ((size_t)bh << 17);

    // ---- staging helpers (identical layouts to R16) ----
    const int rsubK = lane >> 3;                         // 0..7
    const int cswK  = ((lane & 7) ^ rsubK) * 8;          // swizzled src chunk
    const int dV    = w * 8 + (lane >> 3);               // V^T row this thread owns
    const int s3V   = dV & 7;

    auto stageK = [&](int kv0, short* Kt) {
        #pragma unroll
        for (int i2 = 0; i2 < 2; ++i2) {
            const int rb = w * 16 + i2 * 8;
            gl2lds16(Kb + (size_t)(kv0 + rb + rsubK) * 64 + cswK, Kt + rb * 64);
        }
    };
    auto loadV = [&](int kv0, short8* vld) {
        #pragma unroll
        for (int m = 0; m < 2; ++m) {
            const int cm = (lane & 7) + 8 * m;           // 16B piece index
            vld[m] = *(const short8*)(Vb + (size_t)dV * 2048 + kv0 + cm * 8);
        }
    };
    auto writeV = [&](const short8* vld, short* Vp) {
        char* vrow = (char*)Vp + dV * 256;
        #pragma unroll
        for (int m = 0; m < 2; ++m) {
            const int cm = (lane & 7) + 8 * m;
            const int u  = cm >> 3, kk = (cm >> 2) & 1;
            const int q0off = ((cm & 1) << 4) + ((cm >> 1) & 1) * 4;  // shorts
            const int bA = (u * 64 + kk * 32 + q0off) * 2;            // bytes
            const int pA = ((((bA >> 4) ^ s3V) << 4) | (bA & 15));
            const int bB = bA + 16;
            const int pB = ((((bB >> 4) ^ s3V) << 4) | (bB & 15));
            *(short4_t*)(vrow + pA) = __builtin_shufflevector(vld[m], vld[m], 0, 1, 2, 3);
            *(short4_t*)(vrow + pB) = __builtin_shufflevector(vld[m], vld[m], 4, 5, 6, 7);
        }
    };

    // Q as B-operand (pre-scaled by 0.125*log2e at the QKV GEMM):
    // B[n=q=qr0+lm][k=kk*32+lg*8+s]
    short8 qf[2];
    #pragma unroll
    for (int kk = 0; kk < 2; ++kk)
        qf[kk] = *(const short8*)(Qb + (size_t)(qr0 + lm) * DH_ + kk * 32 + lg * 8);

    float m_i = -1e30f, l_i = 0.f;
    v4f o[4] = {};   // O^T[d = i*16+lg*4+r][q = lm]

    // ---- prologue: stage pair 0 into buf0 ----
    short8 vpre[2];
    stageK(0, sm);
    loadV(0, vpre);
    writeV(vpre, sm + 8192);
    __syncthreads();            // drains K DMA (vmcnt) + V writes (lgkm)

    int cur = 0;
    for (int it = 0; it < npairs; ++it) {
        const int kv0 = it * 128;
        const bool dpair = (it == npairs - 1);   // diagonal pair (masked)
        const bool pre   = (it + 1 < npairs);
        short* Kt  = sm + cur * 16384;
        short* Vp  = Kt + 8192;
        short* Ktn = sm + (cur ^ 1) * 16384;
        short* Vpn = Ktn + 8192;

        // ---- prefetch next pair: K DMA into other buf, V into regs ----
        if (pre) {
            stageK(kv0 + 128, Ktn);
            loadV(kv0 + 128, vpre);
        }

        // ---- V^T A-frags from Vp: one swizzled 16B read each ----
        short8 vf[2][2][4];
        #pragma unroll
        for (int u = 0; u < 2; ++u)
            #pragma unroll
            for (int kk = 0; kk < 2; ++kk)
                #pragma unroll
                for (int i = 0; i < 4; ++i) {
                    const int d = i * 16 + lm;
                    const int ch = (u * 8 + kk * 4 + lg) ^ (lm & 7);
                    vf[u][kk][i] = *(const short8*)((const char*)Vp + d * 256 + ch * 16);
                }

        // ---- S^T = K Q^T, both subtiles (16 MFMAs); kf from swizzled Kt ----
        v4f sc[2][4] = {};   // [u][jj]
        #pragma unroll
        for (int u = 0; u < 2; ++u) {
            short8 kf[2][4];
            #pragma unroll
            for (int kk = 0; kk < 2; ++kk)
                #pragma unroll
                for (int jj = 0; jj < 4; ++jj) {
                    const int row = u * 64 + jj * 16 + lm;
                    const int ch  = (kk * 4 + lg) ^ (lm & 7);
                    kf[kk][jj] = *(const short8*)((const char*)Kt + row * 128 + ch * 16);
                }
            #pragma unroll
            for (int kk = 0; kk < 2; ++kk)
                #pragma unroll
                for (int jj = 0; jj < 4; ++jj)
                    sc[u][jj] = __builtin_amdgcn_mfma_f32_16x16x32_bf16(kf[kk][jj], qf[kk], sc[u][jj], 0, 0, 0);
        }

        // one online-softmax step over 128 kv (in-lane 32 + 2 shuffles)
        float alpha;
        short8 pf[2][2];     // [u][kk]
        {
            float x[2][4][4];
            const int q = qr0 + lm;
            #pragma unroll
            for (int u = 0; u < 2; ++u)
                #pragma unroll
                for (int jj = 0; jj < 4; ++jj)
                    #pragma unroll
                    for (int r = 0; r < 4; ++r) {
                        float v = sc[u][jj][r];
                        if (dpair && (kv0 + u * 64 + jj * 16 + lg * 4 + r > q)) v = -1e30f;
                        x[u][jj][r] = v;
                    }
            // tree max over 32 in-lane values
            float m8[8];
            #pragma unroll
            for (int z = 0; z < 8; ++z) {
                const float* xz = x[z >> 2][z & 3];
                m8[z] = fmaxf(fmaxf(xz[0], xz[1]), fmaxf(xz[2], xz[3]));
            }
            float rm = fmaxf(fmaxf(fmaxf(m8[0], m8[1]), fmaxf(m8[2], m8[3])),
                             fmaxf(fmaxf(m8[4], m8[5]), fmaxf(m8[6], m8[7])));
            rm = fmaxf(rm, __shfl_xor(rm, 16, 64));
            rm = fmaxf(rm, __shfl_xor(rm, 32, 64));

            const float mn = fmaxf(m_i, rm);
            alpha = EXP2(m_i - mn);
            m_i = mn;

            // exp2 + tree sum
            float s8[8];
            #pragma unroll
            for (int z = 0; z < 8; ++z) {
                float* xz = x[z >> 2][z & 3];
                xz[0] = EXP2(xz[0] - mn); xz[1] = EXP2(xz[1] - mn);
                xz[2] = EXP2(xz[2] - mn); xz[3] = EXP2(xz[3] - mn);
                s8[z] = (xz[0] + xz[1]) + (xz[2] + xz[3]);
            }
            float rs = ((s8[0] + s8[1]) + (s8[2] + s8[3])) + ((s8[4] + s8[5]) + (s8[6] + s8[7]));
            rs += __shfl_xor(rs, 16, 64);
            rs += __shfl_xor(rs, 32, 64);
            l_i = l_i * alpha + rs;

            // truncating pack: pf[u][kk][jj] = x[u][2kk][jj], [4+jj]=x[u][2kk+1][jj]
            #pragma unroll
            for (int u = 0; u < 2; ++u)
                #pragma unroll
                for (int kk = 0; kk < 2; ++kk) {
                    union { short8 s; uint4 d; } pk;
                    pk.d.x = pack2(x[u][2 * kk][0],     x[u][2 * kk][1]);
                    pk.d.y = pack2(x[u][2 * kk][2],     x[u][2 * kk][3]);
                    pk.d.z = pack2(x[u][2 * kk + 1][0], x[u][2 * kk + 1][1]);
                    pk.d.w = pack2(x[u][2 * kk + 1][2], x[u][2 * kk + 1][3]);
                    pf[u][kk] = pk.s;
                }
        }

        #pragma unroll
        for (int i = 0; i < 4; ++i)
            o[i] *= alpha;

        // O^T += V^T P^T  (16 MFMAs)
        #pragma unroll
        for (int u = 0; u < 2; ++u)
            #pragma unroll
            for (int kk = 0; kk < 2; ++kk)
                #pragma unroll
                for (int i = 0; i < 4; ++i)
                    o[i] = __builtin_amdgcn_mfma_f32_16x16x32_bf16(vf[u][kk][i], pf[u][kk], o[i], 0, 0, 0);

        // ---- write prefetched V into the other buffer, then ONE barrier ----
        if (pre) writeV(vpre, Vpn);
        __syncthreads();   // drains K-DMA (vmcnt) + V ds_writes (lgkm);
                           // all waves' reads of buf[cur] complete
        cur ^= 1;
    }

    // epilogue: ctx[b*S + q][hd*64 + d] = O/l, 8B stores (all waves)
    const int b = bh >> 4, hd = bh & 15;
    {
        const float inv = 1.f / l_i;
        const size_t base = ((size_t)(b * S_ + qr0 + lm) << 10) + (hd << 6) + lg * 4;
        #pragma unroll
        for (int i = 0; i < 4; ++i) {
            short4_t s4;
            #pragma unroll
            for (int r = 0; r < 4; ++r) s4[r] = f2bf(o[i][r] * inv);
            *(short4_t*)(ctx + base + i * 16) = s4;
        }
    }
}

// ---------------------------------------------------------------------------
extern "C" void kernel_launch(void* const* d_in, const int* in_sizes, int n_in,
                              void* d_out, int out_size, void* d_ws, size_t ws_size,
                              hipStream_t stream) {
    const float* X  = (const float*)d_in[0];
    const float* Wq = (const float*)d_in[2];
    const float* bq = (const float*)d_in[3];
    const float* Wk = (const float*)d_in[4];
    const float* bk = (const float*)d_in[5];
    const float* Wv = (const float*)d_in[6];
    const float* bv = (const float*)d_in[7];
    const float* Wo = (const float*)d_in[8];
    const float* bo = (const float*)d_in[9];
    float* out = (float*)d_out;

    short* ws  = (short*)d_ws;
    short* Xb  = ws;                          // X bf16, 4,194,304
    short* Wb  = Xb + 4194304;                // [Wq|Wk|Wv|Wo] bf16
    short* Qh  = Wb + 4194304;                // [bh][s][64]  (pre-scaled)
    short* Kb  = Qh + 4194304;                // [bh][s][64]
    short* Vt  = Kb + 4194304;                // [bh][64][s] (written by gemm)
    short* Ctx = Vt + 4194304;                // [b*s][1024]

    cast_kernel<<<4096, 256, 0, stream>>>(X, Wq, Wk, Wv, Wo, Xb, Wb);

    // fused QKV projection: flat grid 24*32 = 768, swizzled in-kernel
    gemm_kernel<128, 0><<<768, 256, 0, stream>>>(
        Xb, Wb, bq, bk, bv, Qh, M_, 3 * D_, D_);

    // 8-wave double-buffered attention: 512 blocks x 512 threads
    attn_kernel<<<512, 512, 0, stream>>>(Qh, Kb, Vt, Ctx);

    // output projection: flat grid 16*32 = 512, swizzled in-kernel (2/CU)
    gemm_kernel<64, 2><<<512, 256, 0, stream>>>(
        Ctx, Wb + 3145728, bo, bo, bo, out, M_, D_, D_);
}